// Round 3
// baseline (280.920 us; speedup 1.0000x reference)
//
#include <hip/hip_runtime.h>

// BasisEncoder: out[b, :] = one_hot(x[b] % 64, 64) as fp32.
// (x % 256) % 64 == x % 64 since 64 | 256; x >= 0 so & 63 is exact.
//
// R2 strategy: the output is 1M ones in a sea of 64M zeros.
//   1. hipMemsetAsync(d_out, 0, 256 MB) -- zeros at fill rate (~6.4 TB/s
//      demonstrated by the harness's own poison fill).
//   2. scatter kernel: thread b writes out[b*64 + (x[b]&63)] = 1.0f.
//      Reads coalesced (4 MB); writes scattered (1 dword per 256 B row,
//      ~line-granular HBM traffic ~32-64 MB).
// This also discriminates whether R1's single-pass kernel was at the BW
// roofline (then this is slightly slower) or stalled (then this wins).

#define BATCH (1048576)

constexpr int TPB = 256;
constexpr int ROWS_PER_THREAD = 4;
constexpr int BLOCKS = BATCH / (TPB * ROWS_PER_THREAD);   // 1024

typedef int i32x4 __attribute__((ext_vector_type(4)));

__global__ __launch_bounds__(TPB) void basis_scatter_kernel(
    const i32x4* __restrict__ x4, float* __restrict__ out) {
  int t = blockIdx.x * TPB + threadIdx.x;        // [0, BATCH/4)
  i32x4 xv = x4[t];                              // 4 rows' x, 16 B coalesced
  int row0 = t * 4;
  // 4 independent scattered 4 B stores (different 256 B rows).
  out[(size_t)(row0 + 0) * 64 + (xv.x & 63)] = 1.0f;
  out[(size_t)(row0 + 1) * 64 + (xv.y & 63)] = 1.0f;
  out[(size_t)(row0 + 2) * 64 + (xv.z & 63)] = 1.0f;
  out[(size_t)(row0 + 3) * 64 + (xv.w & 63)] = 1.0f;
}

extern "C" void kernel_launch(void* const* d_in, const int* in_sizes, int n_in,
                              void* d_out, int out_size, void* d_ws, size_t ws_size,
                              hipStream_t stream) {
  const i32x4* x4 = (const i32x4*)d_in[0];
  float* out = (float*)d_out;
  // Zero the whole 256 MB output at fill rate (memset node in the graph).
  hipMemsetAsync(d_out, 0, (size_t)out_size * sizeof(float), stream);
  // Then scatter the 1M ones.
  basis_scatter_kernel<<<BLOCKS, TPB, 0, stream>>>(x4, out);
}